// Round 17
// baseline (1409.726 us; speedup 1.0000x reference)
//
#include <hip/hip_runtime.h>
#include <stdint.h>

typedef _Float16 f16;
typedef _Float16 f16x8 __attribute__((ext_vector_type(8)));
typedef float f32x4 __attribute__((ext_vector_type(4)));

#define INF_F __builtin_inff()
#define INF_I 0x7fffffff
#define KM 24            // merge candidate margin
#define KMP 25           // padded LDS stride (25 coprime 32 -> bank-spread)
#define SCALE 262144.0f  // 2^18 fixed-point scale

__device__ __forceinline__ bool lexLess(float s1, int n1, float s2, int n2) {
    return (s1 < s2) || (s1 == s2 && n1 < n2);
}
__device__ __forceinline__ bool lexLessI(int s1, int n1, int s2, int n2) {
    return (s1 < s2) || (s1 == s2 && n1 < n2);
}

__device__ __forceinline__ uint4 pack8(const float4 a, const float4 b) {
    const auto p0 = __builtin_amdgcn_cvt_pkrtz(a.x, a.y);
    const auto p1 = __builtin_amdgcn_cvt_pkrtz(a.z, a.w);
    const auto p2 = __builtin_amdgcn_cvt_pkrtz(b.x, b.y);
    const auto p3 = __builtin_amdgcn_cvt_pkrtz(b.z, b.w);
    uint4 u;
    u.x = __builtin_bit_cast(unsigned, p0);
    u.y = __builtin_bit_cast(unsigned, p1);
    u.z = __builtin_bit_cast(unsigned, p2);
    u.w = __builtin_bit_cast(unsigned, p3);
    return u;
}

// ---------------------------------------------------------------------------
// Kernel 1 (R10 verbatim — best proven: dist ~854 us): k-split streaming
// scores + per-block top-16 per batch row.
// ---------------------------------------------------------------------------
__global__ __launch_bounds__(256, 4) void dist_topk_kernel(
    const float* __restrict__ reps, const float* __restrict__ brep,
    float* __restrict__ cs, int* __restrict__ ci,
    int N, int TT, int NBLK)
{
    __shared__ int slds[64][65];                  // [rep-row][64 dots + ynorm]
    __shared__ int topdI[16][64];
    __shared__ int topiI[16][64];
    __shared__ int thrS[64], thrnS[64], cntS[64];

    const int tid = threadIdx.x;
    const int w = tid >> 6, lane = tid & 63;
    const int li = lane & 15, q = lane >> 4;
    const int b = blockIdx.x;

    uint4 a[4][4];
    #pragma unroll
    for (int ks = 0; ks < 4; ks++)
        #pragma unroll
        for (int mt = 0; mt < 4; mt++) {
            const float* src = brep + (mt * 16 + li) * 512 + 128 * w + 32 * ks + 8 * q;
            const float4 x0 = *(const float4*)(src);
            const float4 x1 = *(const float4*)(src + 4);
            a[ks][mt] = pack8(x0, x1);
        }

    if (tid < 64) { thrS[tid] = INF_I; thrnS[tid] = INF_I; cntS[tid] = 0; }
    for (int i = tid; i < 64 * 65; i += 256) ((int*)slds)[i] = 0;
    __syncthreads();

    int sc = 0;
    for (int t = b; t < TT; t += NBLK, sc++) {
        const int n0 = t * 64;

        #pragma unroll 1
        for (int nsub = 0; nsub < 4; nsub++) {
            const int rowl = n0 + nsub * 16 + li;
            const size_t rowc = (size_t)(rowl < N ? rowl : N - 1);
            const float* bp = reps + rowc * 512 + 128 * w + 8 * q;

            f32x4 acc0 = {0.f,0.f,0.f,0.f}, acc1 = {0.f,0.f,0.f,0.f};
            f32x4 acc2 = {0.f,0.f,0.f,0.f}, acc3 = {0.f,0.f,0.f,0.f};
            float yn = 0.f;

            float4 y0A = *(const float4*)(bp);
            float4 y1A = *(const float4*)(bp + 4);
            #pragma unroll
            for (int ks = 0; ks < 4; ks++) {
                float4 y0B, y1B;
                if (ks < 3) {
                    y0B = *(const float4*)(bp + (ks + 1) * 32);
                    y1B = *(const float4*)(bp + (ks + 1) * 32 + 4);
                }
                yn = fmaf(y0A.x, y0A.x, fmaf(y0A.y, y0A.y, fmaf(y0A.z, y0A.z, fmaf(y0A.w, y0A.w, yn))));
                yn = fmaf(y1A.x, y1A.x, fmaf(y1A.y, y1A.y, fmaf(y1A.z, y1A.z, fmaf(y1A.w, y1A.w, yn))));
                const f16x8 bf = __builtin_bit_cast(f16x8, pack8(y0A, y1A));
                acc0 = __builtin_amdgcn_mfma_f32_16x16x32_f16(__builtin_bit_cast(f16x8, a[ks][0]), bf, acc0, 0, 0, 0);
                acc1 = __builtin_amdgcn_mfma_f32_16x16x32_f16(__builtin_bit_cast(f16x8, a[ks][1]), bf, acc1, 0, 0, 0);
                acc2 = __builtin_amdgcn_mfma_f32_16x16x32_f16(__builtin_bit_cast(f16x8, a[ks][2]), bf, acc2, 0, 0, 0);
                acc3 = __builtin_amdgcn_mfma_f32_16x16x32_f16(__builtin_bit_cast(f16x8, a[ks][3]), bf, acc3, 0, 0, 0);
                if (ks < 3) { y0A = y0B; y1A = y1B; }
            }

            float ys = yn;
            ys += __shfl_xor(ys, 16);
            ys += __shfl_xor(ys, 32);
            const int nloc = nsub * 16 + li;
            if (q == 0) atomicAdd(&slds[nloc][64], __float2int_rn(ys * SCALE));
            #pragma unroll
            for (int jj = 0; jj < 4; jj++) {
                atomicAdd(&slds[nloc][ 0 + 4 * q + jj], __float2int_rn(acc0[jj] * SCALE));
                atomicAdd(&slds[nloc][16 + 4 * q + jj], __float2int_rn(acc1[jj] * SCALE));
                atomicAdd(&slds[nloc][32 + 4 * q + jj], __float2int_rn(acc2[jj] * SCALE));
                atomicAdd(&slds[nloc][48 + 4 * q + jj], __float2int_rn(acc3[jj] * SCALE));
            }
        }

        __syncthreads();   // all atomics of this tile done

        if (w == (sc & 3)) {
            const int r = lane;
            const int* sb = &slds[0][0];
            int thr = thrS[r], thrn = thrnS[r], cnt = cntS[r];
            for (int j = 0; j < 64; j++) {
                const int n = n0 + j;
                if (n >= N) break;
                const int s = sb[j * 65 + 64] - 2 * sb[j * 65 + r];
                if (lexLessI(s, n, thr, thrn)) {
                    if (cnt < 16) {
                        topdI[cnt][r] = s; topiI[cnt][r] = n; cnt++;
                        if (cnt == 16) {
                            int tv = topdI[0][r], tn = topiI[0][r];
                            #pragma unroll
                            for (int u = 1; u < 16; u++) {
                                int v = topdI[u][r], nn = topiI[u][r];
                                if (!lexLessI(v, nn, tv, tn)) { tv = v; tn = nn; }
                            }
                            thr = tv; thrn = tn;
                        }
                    } else {
                        #pragma unroll
                        for (int u = 0; u < 16; u++)
                            if (topdI[u][r] == thr && topiI[u][r] == thrn) {
                                topdI[u][r] = s; topiI[u][r] = n; break;
                            }
                        int tv = topdI[0][r], tn = topiI[0][r];
                        #pragma unroll
                        for (int u = 1; u < 16; u++) {
                            int v = topdI[u][r], nn = topiI[u][r];
                            if (!lexLessI(v, nn, tv, tn)) { tv = v; tn = nn; }
                        }
                        thr = tv; thrn = tn;
                    }
                }
            }
            thrS[r] = thr; thrnS[r] = thrn; cntS[r] = cnt;
            for (int e2 = lane; e2 < 64 * 65; e2 += 64) (&slds[0][0])[e2] = 0;
        }

        __syncthreads();   // slds zeroed before next tile's atomics
    }

    __syncthreads();
    if (tid < 64) {
        const int c = cntS[tid];
        const size_t base = ((size_t)b * 64 + tid) * 16;
        for (int j = 0; j < 16; j++) {
            cs[base + j] = (j < c) ? ((float)topdI[j][tid] * (1.0f / SCALE)) : INF_F;
            ci[base + j] = (j < c) ? topiI[j][tid] : INF_I;
        }
    }
}

// ---------------------------------------------------------------------------
// Kernel 2: merge, SCRATCH-FREE. All per-thread top-KM lists live in LDS
// (runtime-indexed register arrays forced local-memory in every prior
// variant -> the hidden ~380us). Thresholds stay in scalar registers.
// Stage1: 256 threads, top-KM of their stripe of cs/ci -> S1 (LDS).
// Stage2: 32 threads merge 8 lists -> S2 (LDS).
// Stage3: thread 0 merges 32 lists -> F3 (LDS, indices).
// fp64 exact recompute of KM candidates; in-place LDS selection sort;
// softmax weights; action gather; outputs. Content is order-independent.
// ---------------------------------------------------------------------------
__global__ __launch_bounds__(256) void merge_kernel(
    const float* __restrict__ cs, const int* __restrict__ ci,
    const float* __restrict__ brep, const float* __restrict__ reps,
    const float* __restrict__ acts,
    float* __restrict__ out, int NLISTS, int N, int BA)
{
    const int r = blockIdx.x;
    const int tid = threadIdx.x;
    __shared__ __align__(16) float xrow[512];
    __shared__ float S1s[256 * KMP];
    __shared__ int   S1i[256 * KMP];
    __shared__ float S2s[32 * KMP];
    __shared__ int   S2i[32 * KMP];
    __shared__ float F3s[KM];
    __shared__ int   F3i[KM];
    __shared__ double fd[KM];
    __shared__ int    fn[KM];

    if (tid < 128)
        *(float4*)(&xrow[tid * 4]) = *(const float4*)(&brep[(size_t)r * 512 + tid * 4]);

    // ---- stage 1: per-thread top-KM, list in LDS, threshold in registers ----
    {
        float* Ls = S1s + tid * KMP;
        int*   Li = S1i + tid * KMP;
        #pragma unroll
        for (int j = 0; j < KM; j++) { Ls[j] = INF_F; Li[j] = INF_I; }
        float mv = INF_F; int mn = INF_I; int mp = 0;
        const int total = NLISTS * 16;
        for (int e = tid; e < total; e += 256) {
            const int blk = e >> 4, j = e & 15;
            const size_t a = (size_t)blk * 1024 + (size_t)r * 16 + j;
            const float s = cs[a]; const int n = ci[a];
            if (lexLess(s, n, mv, mn)) {
                Ls[mp] = s; Li[mp] = n;
                mv = Ls[0]; mn = Li[0]; mp = 0;
                #pragma unroll
                for (int u = 1; u < KM; u++) {
                    const float v = Ls[u]; const int nn = Li[u];
                    if (!lexLess(v, nn, mv, mn)) { mv = v; mn = nn; mp = u; }
                }
            }
        }
    }
    __syncthreads();

    // ---- stage 2: 32 threads merge 8 lists each -> S2 (LDS) ----
    if (tid < 32) {
        float* Ms = S2s + tid * KMP;
        int*   Mi = S2i + tid * KMP;
        #pragma unroll
        for (int j = 0; j < KM; j++) { Ms[j] = INF_F; Mi[j] = INF_I; }
        float mv = INF_F; int mn = INF_I; int mp = 0;
        for (int l = 0; l < 8; l++) {
            const float* Ls = S1s + (tid * 8 + l) * KMP;
            const int*   Li = S1i + (tid * 8 + l) * KMP;
            #pragma unroll
            for (int j = 0; j < KM; j++) {
                const float s = Ls[j]; const int n = Li[j];
                if (lexLess(s, n, mv, mn)) {
                    Ms[mp] = s; Mi[mp] = n;
                    mv = Ms[0]; mn = Mi[0]; mp = 0;
                    #pragma unroll
                    for (int u = 1; u < KM; u++) {
                        const float v = Ms[u]; const int nn = Mi[u];
                        if (!lexLess(v, nn, mv, mn)) { mv = v; mn = nn; mp = u; }
                    }
                }
            }
        }
    }
    __syncthreads();

    // ---- stage 3: thread 0 merges 32 lists -> F3 (LDS) ----
    if (tid == 0) {
        #pragma unroll
        for (int j = 0; j < KM; j++) { F3s[j] = INF_F; F3i[j] = INF_I; }
        float mv = INF_F; int mn = INF_I; int mp = 0;
        for (int l = 0; l < 32; l++) {
            const float* Ms = S2s + l * KMP;
            const int*   Mi = S2i + l * KMP;
            #pragma unroll
            for (int j = 0; j < KM; j++) {
                const float s = Ms[j]; const int n = Mi[j];
                if (lexLess(s, n, mv, mn)) {
                    F3s[mp] = s; F3i[mp] = n;
                    mv = F3s[0]; mn = F3i[0]; mp = 0;
                    #pragma unroll
                    for (int u = 1; u < KM; u++) {
                        const float v = F3s[u]; const int nn = F3i[u];
                        if (!lexLess(v, nn, mv, mn)) { mv = v; mn = nn; mp = u; }
                    }
                }
            }
        }
    }
    __syncthreads();

    // ---- fp64 exact recompute of the KM candidates ----
    if (tid < KM) {
        const int n = F3i[tid];
        fn[tid] = n;
        double d = 1.0e300;
        if (n >= 0 && n < N) {
            double d0a = 0.0, d1a = 0.0, d2a = 0.0, d3a = 0.0;
            const float* yp = reps + (size_t)n * 512;
            for (int i = 0; i < 512; i += 4) {
                float4 yv = *(const float4*)(yp + i);
                double e0 = (double)xrow[i + 0] - (double)yv.x;
                double e1 = (double)xrow[i + 1] - (double)yv.y;
                double e2 = (double)xrow[i + 2] - (double)yv.z;
                double e3 = (double)xrow[i + 3] - (double)yv.w;
                d0a += e0 * e0; d1a += e1 * e1; d2a += e2 * e2; d3a += e3 * e3;
            }
            d = (d0a + d1a) + (d2a + d3a);
        }
        fd[tid] = d;
    }
    __syncthreads();

    // ---- exact in-place LDS selection sort (d, n) lexicographic; outputs ----
    if (tid == 0) {
        for (int a2 = 0; a2 < 16; a2++) {
            int best = a2;
            for (int u = a2 + 1; u < KM; u++)
                if (fd[u] < fd[best] || (fd[u] == fd[best] && fn[u] < fn[best])) best = u;
            double td = fd[a2]; fd[a2] = fd[best]; fd[best] = td;
            int tn = fn[a2]; fn[a2] = fn[best]; fn[best] = tn;
        }
        double dist[16];
        #pragma unroll
        for (int j = 0; j < 16; j++) {
            const double v = fd[j];
            dist[j] = sqrt(v > 0.0 ? v : 0.0);
        }
        double wv[16], wsum = 0.0;
        #pragma unroll
        for (int j = 0; j < 16; j++) { wv[j] = exp(dist[0] - dist[j]); wsum += wv[j]; }
        for (int a2 = 0; a2 < 7; a2++) {
            double s = 0.0;
            #pragma unroll
            for (int j = 0; j < 16; j++)
                s += wv[j] * (double)acts[(size_t)fn[j] * 7 + a2];
            out[r * 7 + a2] = (float)(s / wsum);
        }
        for (int j = 0; j < 16; j++)
            out[BA + r * 16 + j] = (float)fn[j];
    }
}

extern "C" void kernel_launch(void* const* d_in, const int* in_sizes, int n_in,
                              void* d_out, int out_size, void* d_ws, size_t ws_size,
                              hipStream_t stream) {
    const float* brep = (const float*)d_in[0];
    const float* reps = (const float*)d_in[1];
    const float* acts = (const float*)d_in[2];
    const int D = 512;
    const int B = in_sizes[0] / D;   // 64
    const int N = in_sizes[1] / D;   // 500000
    float* out = (float*)d_out;

    // 1024 blocks = 4/CU (25.6 KB LDS) — R10 config.
    int NBLK = 1024;
    const size_t perblk = (size_t)64 * 16 * 8;        // cs+ci bytes per block
    while (NBLK > 1 && (size_t)NBLK * perblk > ws_size) NBLK >>= 1;

    float* cs = (float*)d_ws;
    int* ci = (int*)((char*)d_ws + (size_t)NBLK * 64 * 16 * 4);

    const int TT = (N + 63) / 64;                     // 64-row tiles

    dist_topk_kernel<<<NBLK, 256, 0, stream>>>(reps, brep, cs, ci, N, TT, NBLK);
    merge_kernel<<<B, 256, 0, stream>>>(cs, ci, brep, reps, acts, out, NBLK, N, B * 7);
}